// Round 1
// baseline (142.531 us; speedup 1.0000x reference)
//
#include <hip/hip_runtime.h>
#include <math.h>

#define EPS_F 1e-6f

__global__ __launch_bounds__(256) void traj_kernel(
    const float4* __restrict__ q_prev,
    const float4* __restrict__ q_curr,
    const float*  __restrict__ w1,   // [16][8]
    const float*  __restrict__ b1,   // [16]
    const float*  __restrict__ w2,   // [4][16]
    const float*  __restrict__ b2,   // [4]
    const float*  __restrict__ t_steps, // [10]
    float4*       __restrict__ out,  // [B][10] float4
    int B)
{
    int i = blockIdx.x * blockDim.x + threadIdx.x;
    if (i >= B) return;

    const float4 qp = q_prev[i];
    const float4 qc = q_curr[i];

    float in8[8] = {qp.x, qp.y, qp.z, qp.w, qc.x, qc.y, qc.z, qc.w};

    // ---- layer 1: h = tanh(W1 @ in + b1) ----
    float h[16];
#pragma unroll
    for (int j = 0; j < 16; ++j) {
        float acc = b1[j];
#pragma unroll
        for (int k = 0; k < 8; ++k) acc = fmaf(w1[j * 8 + k], in8[k], acc);
        // tanh(x) = 1 - 2/(exp(2x)+1)  (exact identity; __expf ~1ulp)
        float e = __expf(2.0f * acc);
        h[j] = 1.0f - 2.0f / (e + 1.0f);
    }

    // ---- layer 2: vc = W2 @ h + b2 ----
    float vc[4];
#pragma unroll
    for (int j = 0; j < 4; ++j) {
        float acc = b2[j];
#pragma unroll
        for (int k = 0; k < 16; ++k) acc = fmaf(w2[j * 16 + k], h[k], acc);
        vc[j] = acc;
    }

    // ---- delta_q = quat_mul(q_curr, conj(q_prev)) ----
    // quaternion layout: (.x=w, .y=x, .z=y, .w=z)
    float dw =  qc.x*qp.x + qc.y*qp.y + qc.z*qp.z + qc.w*qp.w;
    float dx = -qc.x*qp.y + qc.y*qp.x - qc.z*qp.w + qc.w*qp.z;
    float dy = -qc.x*qp.z + qc.y*qp.w + qc.z*qp.x - qc.w*qp.y;
    float dz = -qc.x*qp.w - qc.y*qp.z + qc.z*qp.y + qc.w*qp.x;

    // ---- omega = 2*quat_log(delta_q); unit axis + magnitude ----
    float vn  = sqrtf(dx*dx + dy*dy + dz*dz);
    float wcl = fminf(fmaxf(dw, -1.0f), 1.0f);
    float ang = acosf(wcl);                 // [0, pi]
    bool  safe = (vn >= EPS_F);
    float inv_vn = safe ? (1.0f / vn) : 0.0f;
    float ux = dx * inv_vn, uy = dy * inv_vn, uz = dz * inv_vn;
    float on = safe ? (2.0f * ang) : 0.0f;  // |omega|

    // ---- horizon loop ----
#pragma unroll
    for (int st = 0; st < 10; ++st) {
        float t  = t_steps[st];
        float th = on * t;
        float s, c;
        __sincosf(th, &s, &c);
        float ax = s * ux, ay = s * uy, az = s * uz;

        // q_pred = quat_mul((c,ax,ay,az), qc)
        float pw = c*qc.x - ax*qc.y - ay*qc.z - az*qc.w;
        float px = c*qc.y + ax*qc.x + ay*qc.w - az*qc.z;
        float py = c*qc.z - ax*qc.w + ay*qc.x + az*qc.y;
        float pz = c*qc.w + ax*qc.z - ay*qc.y + az*qc.x;

        float tf = t * 0.1f;
        pw = fmaf(vc[0], tf, pw);
        px = fmaf(vc[1], tf, px);
        py = fmaf(vc[2], tf, py);
        pz = fmaf(vc[3], tf, pz);

        float n2 = pw*pw + px*px + py*py + pz*pz;
        float r  = rsqrtf(fmaxf(n2, 1e-24f));
        out[(size_t)i * 10 + st] = make_float4(pw*r, px*r, py*r, pz*r);
    }
}

extern "C" void kernel_launch(void* const* d_in, const int* in_sizes, int n_in,
                              void* d_out, int out_size, void* d_ws, size_t ws_size,
                              hipStream_t stream) {
    const float4* q_prev  = (const float4*)d_in[0];
    const float4* q_curr  = (const float4*)d_in[1];
    const float*  w1      = (const float*)d_in[2];
    const float*  b1      = (const float*)d_in[3];
    const float*  w2      = (const float*)d_in[4];
    const float*  b2      = (const float*)d_in[5];
    const float*  t_steps = (const float*)d_in[6];
    float4*       out     = (float4*)d_out;

    int B = in_sizes[0] / 4;
    int block = 256;
    int grid = (B + block - 1) / block;
    traj_kernel<<<grid, block, 0, stream>>>(q_prev, q_curr, w1, b1, w2, b2,
                                            t_steps, out, B);
}

// Round 3
// 84.784 us; speedup vs baseline: 1.6811x; 1.6811x over previous
//
#include <hip/hip_runtime.h>
#include <math.h>

#define EPS_F 1e-6f
#define BLOCK 128
#define STRIDE_DW 44   // 40 data dwords + 4 pad; 16B-aligned, bank-spread

__global__ __launch_bounds__(BLOCK) void traj_kernel(
    const float4* __restrict__ q_prev,
    const float4* __restrict__ q_curr,
    const float*  __restrict__ w1,   // [16][8]
    const float*  __restrict__ b1,   // [16]
    const float*  __restrict__ w2,   // [4][16]
    const float*  __restrict__ b2,   // [4]
    const float*  __restrict__ t_steps, // [10]
    float4*       __restrict__ out,  // [B*10] float4
    int B)
{
    __shared__ float lds[BLOCK * STRIDE_DW];   // 22528 B

    const int tid = threadIdx.x;
    int i = blockIdx.x * BLOCK + tid;
    if (i >= B) i = B - 1;               // clamp; keep barrier-safe

    const float4 qp = q_prev[i];
    const float4 qc = q_curr[i];

    float in8[8] = {qp.x, qp.y, qp.z, qp.w, qc.x, qc.y, qc.z, qc.w};

    // ---- layer 1: h = tanh(W1 @ in + b1) ----
    float h[16];
#pragma unroll
    for (int j = 0; j < 16; ++j) {
        float acc = b1[j];
#pragma unroll
        for (int k = 0; k < 8; ++k) acc = fmaf(w1[j * 8 + k], in8[k], acc);
        float e = __expf(2.0f * acc);            // tanh = 1 - 2/(e^{2x}+1)
        h[j] = 1.0f - 2.0f / (e + 1.0f);
    }

    // ---- layer 2: vc = W2 @ h + b2 ----
    float vc[4];
#pragma unroll
    for (int j = 0; j < 4; ++j) {
        float acc = b2[j];
#pragma unroll
        for (int k = 0; k < 16; ++k) acc = fmaf(w2[j * 16 + k], h[k], acc);
        vc[j] = acc;
    }

    // ---- delta_q = quat_mul(q_curr, conj(q_prev)); (.x=w,.y=x,.z=y,.w=z) ----
    float dw =  qc.x*qp.x + qc.y*qp.y + qc.z*qp.z + qc.w*qp.w;
    float dx = -qc.x*qp.y + qc.y*qp.x - qc.z*qp.w + qc.w*qp.z;
    float dy = -qc.x*qp.z + qc.y*qp.w + qc.z*qp.x - qc.w*qp.y;
    float dz = -qc.x*qp.w - qc.y*qp.z + qc.z*qp.y + qc.w*qp.x;

    // ---- omega magnitude + unit axis ----
    float vn  = sqrtf(dx*dx + dy*dy + dz*dz);
    float wcl = fminf(fmaxf(dw, -1.0f), 1.0f);
    float ang = acosf(wcl);
    bool  safe = (vn >= EPS_F);
    float inv_vn = safe ? (1.0f / vn) : 0.0f;
    float ux = dx * inv_vn, uy = dy * inv_vn, uz = dz * inv_vn;
    float on = safe ? (2.0f * ang) : 0.0f;

    // ---- horizon loop: results -> LDS ----
#pragma unroll
    for (int st = 0; st < 10; ++st) {
        float t  = t_steps[st];
        float th = on * t;
        float s, c;
        __sincosf(th, &s, &c);
        float ax = s * ux, ay = s * uy, az = s * uz;

        float pw = c*qc.x - ax*qc.y - ay*qc.z - az*qc.w;
        float px = c*qc.y + ax*qc.x + ay*qc.w - az*qc.z;
        float py = c*qc.z - ax*qc.w + ay*qc.x + az*qc.y;
        float pz = c*qc.w + ax*qc.z - ay*qc.y + az*qc.x;

        float tf = t * 0.1f;
        pw = fmaf(vc[0], tf, pw);
        px = fmaf(vc[1], tf, px);
        py = fmaf(vc[2], tf, py);
        pz = fmaf(vc[3], tf, pz);

        float n2 = pw*pw + px*px + py*py + pz*pz;
        float r  = rsqrtf(fmaxf(n2, 1e-24f));

        *(float4*)&lds[tid * STRIDE_DW + st * 4] =
            make_float4(pw*r, px*r, py*r, pz*r);
    }

    __syncthreads();

    // ---- coalesced block-contiguous output write ----
    const size_t base_f4  = (size_t)blockIdx.x * (BLOCK * 10);
    const size_t total_f4 = (size_t)B * 10;
#pragma unroll
    for (int k = 0; k < 10; ++k) {
        int g = k * BLOCK + tid;            // float4 index within block region
        int e = g / 10;                     // element slot in LDS
        int s = g - e * 10;                 // step
        float4 v = *(const float4*)&lds[e * STRIDE_DW + s * 4];
        size_t gi = base_f4 + (size_t)g;
        if (gi < total_f4) out[gi] = v;
    }
}

extern "C" void kernel_launch(void* const* d_in, const int* in_sizes, int n_in,
                              void* d_out, int out_size, void* d_ws, size_t ws_size,
                              hipStream_t stream) {
    const float4* q_prev  = (const float4*)d_in[0];
    const float4* q_curr  = (const float4*)d_in[1];
    const float*  w1      = (const float*)d_in[2];
    const float*  b1      = (const float*)d_in[3];
    const float*  w2      = (const float*)d_in[4];
    const float*  b2      = (const float*)d_in[5];
    const float*  t_steps = (const float*)d_in[6];
    float4*       out     = (float4*)d_out;

    int B = in_sizes[0] / 4;
    int grid = (B + BLOCK - 1) / BLOCK;
    traj_kernel<<<grid, BLOCK, 0, stream>>>(q_prev, q_curr, w1, b1, w2, b2,
                                            t_steps, out, B);
}

// Round 4
// 84.158 us; speedup vs baseline: 1.6936x; 1.0074x over previous
//
#include <hip/hip_runtime.h>
#include <math.h>

#define EPS_F 1e-6f
#define BLOCK 128
#define STRIDE_DW 44   // per-element LDS stride (dwords): 16B-aligned, spreads all 32 banks

// Two element-passes share one 64-element LDS buffer (11264 B) so LDS/block is
// halved vs staging all 128 elements -> 14 blocks/CU = 28 waves/CU instead of 14.
__global__ __launch_bounds__(BLOCK, 7) void traj_kernel(
    const float4* __restrict__ q_prev,
    const float4* __restrict__ q_curr,
    const float*  __restrict__ w1,   // [16][8]
    const float*  __restrict__ b1,   // [16]
    const float*  __restrict__ w2,   // [4][16]
    const float*  __restrict__ b2,   // [4]
    const float*  __restrict__ t_steps, // [10]
    float4*       __restrict__ out,  // [B*10] float4
    int B)
{
    __shared__ float lds[64 * STRIDE_DW];   // 11264 B

    const int tid = threadIdx.x;
    int i = blockIdx.x * BLOCK + tid;
    if (i >= B) i = B - 1;               // defensive clamp (B % BLOCK == 0 in practice)

    const float4 qp = q_prev[i];
    const float4 qc = q_curr[i];

    float in8[8] = {qp.x, qp.y, qp.z, qp.w, qc.x, qc.y, qc.z, qc.w};

    // ---- layer 1: h = tanh(W1 @ in + b1) ----
    float h[16];
#pragma unroll
    for (int j = 0; j < 16; ++j) {
        float acc = b1[j];
#pragma unroll
        for (int k = 0; k < 8; ++k) acc = fmaf(w1[j * 8 + k], in8[k], acc);
        float e = __expf(2.0f * acc);            // tanh = 1 - 2/(e^{2x}+1)
        h[j] = 1.0f - 2.0f / (e + 1.0f);
    }

    // ---- layer 2: vc = W2 @ h + b2 ----
    float vc[4];
#pragma unroll
    for (int j = 0; j < 4; ++j) {
        float acc = b2[j];
#pragma unroll
        for (int k = 0; k < 16; ++k) acc = fmaf(w2[j * 16 + k], h[k], acc);
        vc[j] = acc;
    }

    // ---- delta_q = quat_mul(q_curr, conj(q_prev)); (.x=w,.y=x,.z=y,.w=z) ----
    float dw =  qc.x*qp.x + qc.y*qp.y + qc.z*qp.z + qc.w*qp.w;
    float dx = -qc.x*qp.y + qc.y*qp.x - qc.z*qp.w + qc.w*qp.z;
    float dy = -qc.x*qp.z + qc.y*qp.w + qc.z*qp.x - qc.w*qp.y;
    float dz = -qc.x*qp.w - qc.y*qp.z + qc.z*qp.y + qc.w*qp.x;

    // ---- omega magnitude + unit axis ----
    float vn  = sqrtf(dx*dx + dy*dy + dz*dz);
    float wcl = fminf(fmaxf(dw, -1.0f), 1.0f);
    float ang = acosf(wcl);
    bool  safe = (vn >= EPS_F);
    float inv_vn = safe ? (1.0f / vn) : 0.0f;
    float ux = dx * inv_vn, uy = dy * inv_vn, uz = dz * inv_vn;
    float on = safe ? (2.0f * ang) : 0.0f;

    const size_t base = (size_t)blockIdx.x * (BLOCK * 10);   // float4 units

    // ---- two element-passes sharing the LDS buffer ----
#pragma unroll
    for (int p = 0; p < 2; ++p) {
        if ((tid >> 6) == p) {               // wave-uniform branch: wave p stages
            const int el = tid & 63;
#pragma unroll
            for (int st = 0; st < 10; ++st) {
                float t  = t_steps[st];
                float th = on * t;
                float s, c;
                __sincosf(th, &s, &c);
                float ax = s * ux, ay = s * uy, az = s * uz;

                float pw = c*qc.x - ax*qc.y - ay*qc.z - az*qc.w;
                float px = c*qc.y + ax*qc.x + ay*qc.w - az*qc.z;
                float py = c*qc.z - ax*qc.w + ay*qc.x + az*qc.y;
                float pz = c*qc.w + ax*qc.z - ay*qc.y + az*qc.x;

                float tf = t * 0.1f;
                pw = fmaf(vc[0], tf, pw);
                px = fmaf(vc[1], tf, px);
                py = fmaf(vc[2], tf, py);
                pz = fmaf(vc[3], tf, pz);

                float n2 = pw*pw + px*px + py*py + pz*pz;
                float r  = rsqrtf(fmaxf(n2, 1e-24f));

                *(float4*)&lds[el * STRIDE_DW + st * 4] =
                    make_float4(pw*r, px*r, py*r, pz*r);
            }
        }
        __syncthreads();

        // drain: 640 contiguous float4 (10 KB), lane-consecutive -> fully coalesced
#pragma unroll
        for (int k = 0; k < 5; ++k) {
            int g = k * BLOCK + tid;         // [0, 640)
            int e = g / 10;
            int s = g - e * 10;
            float4 v = *(const float4*)&lds[e * STRIDE_DW + s * 4];
            out[base + (size_t)p * 640 + g] = v;
        }
        if (p == 0) __syncthreads();         // protect buffer before pass-1 writes
    }
}

extern "C" void kernel_launch(void* const* d_in, const int* in_sizes, int n_in,
                              void* d_out, int out_size, void* d_ws, size_t ws_size,
                              hipStream_t stream) {
    const float4* q_prev  = (const float4*)d_in[0];
    const float4* q_curr  = (const float4*)d_in[1];
    const float*  w1      = (const float*)d_in[2];
    const float*  b1      = (const float*)d_in[3];
    const float*  w2      = (const float*)d_in[4];
    const float*  b2      = (const float*)d_in[5];
    const float*  t_steps = (const float*)d_in[6];
    float4*       out     = (float4*)d_out;

    int B = in_sizes[0] / 4;
    int grid = (B + BLOCK - 1) / BLOCK;
    traj_kernel<<<grid, BLOCK, 0, stream>>>(q_prev, q_curr, w1, b1, w2, b2,
                                            t_steps, out, B);
}